// Round 4
// baseline (13547.891 us; speedup 1.0000x reference)
//
#include <hip/hip_runtime.h>

#define HIDDEN 32
#define FF 40
#define SEQ_T 512
#define NW 4        // waves per block (FF split across waves)
#define SL 10       // FF columns per wave

// ws layout (float offsets):
//   WS_BH[40], WS_BO[40] : fused biases (t>=1):  b1* + b2hh @ W1*[:32]
//   WS_UH[40], WS_UO[40] : input weights W1*[32,:]
//   WS_P [4][40][20]     : per-wave packed weights; for wave w, row j:
//        q in [0,10):  A[j][w*10+q]   (A  = W2hh @ W1hh[:32])
//        q in [10,20): Bm[j][w*10+q-10] (Bm = W2hh @ W1ho[:32])
//   3360 floats total; float4-aligned (WS_P % 4 == 0).
#define WS_BH 0
#define WS_BO 40
#define WS_UH 80
#define WS_UO 120
#define WS_P  160

__global__ __launch_bounds__(256, 1) void rnn_prep(
    const float* __restrict__ W1hh, const float* __restrict__ b1hh,
    const float* __restrict__ W2hh, const float* __restrict__ b2hh,
    const float* __restrict__ W1ho, const float* __restrict__ b1ho,
    float* __restrict__ ws)
{
    const int t = threadIdx.x;
    // packed fused matrices: 3200 entries, each a 32-term dot
    for (int idx = t; idx < NW * FF * 2 * SL; idx += 256) {
        const int w  = idx / (FF * 2 * SL);
        const int r2 = idx % (FF * 2 * SL);
        const int j  = r2 / (2 * SL);
        const int q  = r2 % (2 * SL);
        const float* M = (q < SL) ? W1hh : W1ho;
        const int col = w * SL + (q % SL);
        float acc = 0.f;
        for (int i = 0; i < HIDDEN; ++i)
            acc = __builtin_fmaf(W2hh[j * HIDDEN + i], M[i * FF + col], acc);
        ws[WS_P + idx] = acc;
    }
    if (t < FF) {
        float bh = b1hh[t], bo = b1ho[t];
        for (int i = 0; i < HIDDEN; ++i) {
            bh = __builtin_fmaf(b2hh[i], W1hh[i * FF + t], bh);
            bo = __builtin_fmaf(b2hh[i], W1ho[i * FF + t], bo);
        }
        ws[WS_BH + t] = bh;
        ws[WS_BO + t] = bo;
        ws[WS_UH + t] = W1hh[HIDDEN * FF + t];
        ws[WS_UO + t] = W1ho[HIDDEN * FF + t];
    }
}

__device__ __forceinline__ float sigmoid_fast(float x) {
    const float e = __builtin_amdgcn_exp2f(-x * 1.44269504088896341f);
    return __builtin_amdgcn_rcpf(1.0f + e);
}

// Block = 256 threads = 4 waves covering 64 rows (lane = row).
// Wave w owns FF columns [10w,10w+10). Weights stream through VMEM (vmcnt)
// as broadcast float4 loads — opaque-zero VGPR index defeats SMEM selection
// so they never share lgkmcnt with the ds_read s-exchange (the R3 stall).
__global__ __launch_bounds__(256, 1) void rnn_main(
    const float* __restrict__ inputs,
    const float* __restrict__ ws,
    const float* __restrict__ b1hh, const float* __restrict__ b1ho,
    const float* __restrict__ W2ho, const float* __restrict__ b2ho,
    float* __restrict__ ys)
{
    const int lane = threadIdx.x & 63;
    const int w = __builtin_amdgcn_readfirstlane(threadIdx.x >> 6); // 0..3
    const int jb = w * SL;                                          // uniform
    const int r = blockIdx.x * 64 + lane;
    const float* __restrict__ in_row = inputs + (size_t)r * SEQ_T;
    float* __restrict__ out_row = ys + (size_t)r * SEQ_T;

    const float* __restrict__ bhh = ws + WS_BH;
    const float* __restrict__ bho = ws + WS_BO;
    const float* __restrict__ uhh = ws + WS_UH;
    const float* __restrict__ uho = ws + WS_UO;
    const float4* __restrict__ Pw = (const float4*)(ws + WS_P + w * (FF * 2 * SL));

    int vz;
    asm volatile("v_mov_b32 %0, 0" : "=v"(vz));  // opaque 0 -> forces VMEM path

    __shared__ float s_ex[2][FF][64];
    __shared__ float o_ex[2][NW][64];

    // ---- step 0: h(0)=0 -> z = u*wu + b1 (raw layer-1 bias) ----
    float u = in_row[0];
    {
        float z[SL], zo[SL], op = 0.f;
#pragma unroll
        for (int k = 0; k < SL; ++k) {
            z[k]  = __builtin_fmaf(u, uhh[jb + k], b1hh[jb + k]);
            zo[k] = __builtin_fmaf(u, uho[jb + k], b1ho[jb + k]);
            z[k]  = sigmoid_fast(z[k]);
            op = __builtin_fmaf(sigmoid_fast(zo[k]), W2ho[jb + k], op);
            s_ex[0][jb + k][lane] = z[k];
        }
        o_ex[0][w][lane] = op;
    }
    float un = in_row[1];
    __syncthreads();

    const float b2o = b2ho[0];

    for (int t = 1; t < SEQ_T; ++t) {
        const int rb = (t - 1) & 1;
        const int wb = t & 1;

        // one wave (rotating) reduces o(t-1) and stores it
        if (w == ((t - 1) & 3)) {
            float o = o_ex[rb][0][lane] + o_ex[rb][1][lane]
                    + o_ex[rb][2][lane] + o_ex[rb][3][lane] + b2o;
            out_row[t - 1] = o;
        }

        u = un;
        float z[SL], zo[SL];
#pragma unroll
        for (int k = 0; k < SL; ++k) {
            z[k]  = __builtin_fmaf(u, uhh[jb + k], bhh[jb + k]);
            zo[k] = __builtin_fmaf(u, uho[jb + k], bho[jb + k]);
        }
#pragma unroll
        for (int j = 0; j < FF; ++j) {
            const float sj = s_ex[rb][j][lane];        // ds_read_b32, 2-way = free
            const float4 w0 = Pw[vz + j * 5 + 0];      // A[0..3]
            const float4 w1 = Pw[vz + j * 5 + 1];      // A[4..7]
            const float4 w2 = Pw[vz + j * 5 + 2];      // A[8..9], Bm[0..1]
            const float4 w3 = Pw[vz + j * 5 + 3];      // Bm[2..5]
            const float4 w4 = Pw[vz + j * 5 + 4];      // Bm[6..9]
            z[0] = __builtin_fmaf(sj, w0.x, z[0]);
            z[1] = __builtin_fmaf(sj, w0.y, z[1]);
            z[2] = __builtin_fmaf(sj, w0.z, z[2]);
            z[3] = __builtin_fmaf(sj, w0.w, z[3]);
            z[4] = __builtin_fmaf(sj, w1.x, z[4]);
            z[5] = __builtin_fmaf(sj, w1.y, z[5]);
            z[6] = __builtin_fmaf(sj, w1.z, z[6]);
            z[7] = __builtin_fmaf(sj, w1.w, z[7]);
            z[8] = __builtin_fmaf(sj, w2.x, z[8]);
            z[9] = __builtin_fmaf(sj, w2.y, z[9]);
            zo[0] = __builtin_fmaf(sj, w2.z, zo[0]);
            zo[1] = __builtin_fmaf(sj, w2.w, zo[1]);
            zo[2] = __builtin_fmaf(sj, w3.x, zo[2]);
            zo[3] = __builtin_fmaf(sj, w3.y, zo[3]);
            zo[4] = __builtin_fmaf(sj, w3.z, zo[4]);
            zo[5] = __builtin_fmaf(sj, w3.w, zo[5]);
            zo[6] = __builtin_fmaf(sj, w4.x, zo[6]);
            zo[7] = __builtin_fmaf(sj, w4.y, zo[7]);
            zo[8] = __builtin_fmaf(sj, w4.z, zo[8]);
            zo[9] = __builtin_fmaf(sj, w4.w, zo[9]);
        }

        float op = 0.f;
#pragma unroll
        for (int k = 0; k < SL; ++k) {
            const float sk = sigmoid_fast(z[k]);          // s(t) slice
            op = __builtin_fmaf(sigmoid_fast(zo[k]), W2ho[jb + k], op);
            s_ex[wb][jb + k][lane] = sk;
        }
        o_ex[wb][w][lane] = op;

        un = in_row[t < SEQ_T - 1 ? t + 1 : SEQ_T - 1];   // prefetch next u
        __syncthreads();
    }

    // epilogue: o(511) lives in buffer (511 & 1) = 1
    if (w == ((SEQ_T - 1) & 3)) {
        float o = o_ex[1][0][lane] + o_ex[1][1][lane]
                + o_ex[1][2][lane] + o_ex[1][3][lane] + b2o;
        out_row[SEQ_T - 1] = o;
    }
}

extern "C" void kernel_launch(void* const* d_in, const int* in_sizes, int n_in,
                              void* d_out, int out_size, void* d_ws, size_t ws_size,
                              hipStream_t stream) {
    const float* inputs = (const float*)d_in[0];
    const float* W1hh   = (const float*)d_in[1];
    const float* b1hh   = (const float*)d_in[2];
    const float* W2hh   = (const float*)d_in[3];
    const float* b2hh   = (const float*)d_in[4];
    const float* W1ho   = (const float*)d_in[5];
    const float* b1ho   = (const float*)d_in[6];
    const float* W2ho   = (const float*)d_in[7];
    const float* b2ho   = (const float*)d_in[8];
    float* ys = (float*)d_out;
    float* ws = (float*)d_ws;

    const int B = in_sizes[0] / SEQ_T;   // 16384

    rnn_prep<<<1, 256, 0, stream>>>(W1hh, b1hh, W2hh, b2hh, W1ho, b1ho, ws);

    const int blocks = B / 64;           // 256 blocks of 4 waves
    rnn_main<<<blocks, 256, 0, stream>>>(inputs, ws, b1hh, b1ho, W2ho, b2ho, ys);
}

// Round 5
// 630.062 us; speedup vs baseline: 21.5025x; 21.5025x over previous
//
#include <hip/hip_runtime.h>

#define HIDDEN 32
#define FF 40
#define SEQ_T 512

typedef __attribute__((ext_vector_type(8))) short short8;
typedef __attribute__((ext_vector_type(4))) float float4v;

// ---------------------------------------------------------------------------
// Fused algebra (verified R3): h is linear in s=sigma(z_hh), so eliminate h:
//   z(t)  = s(t-1) @ A  + u(t)*wu_hh + beta_hh      (40 cols, hh path)
//   zo(t) = s(t-1) @ Bm + u(t)*wu_ho + beta_ho      (40 cols, ho path)
//   o(t)  = sigma(zo(t)) @ W2ho + b2ho
// Acat = [A | Bm] padded to K=64 x N=96 (6 N-tiles of 16).
//   k 0..39 = s-weights, k=40 = wu row, k=41 = beta row (S channel = 1.0),
//   k 42..63 = 0.  n 0..39 hh (pad 40..47), n 48..87 ho (pad 88..95).
// Split precision: Acat = Ahi + Alo (bf16 each), S = Shi + Slo (bf16 each);
//   Z = Shi@Ahi + Slo@Ahi + Shi@Alo  (error ~2^-17, fp32-quality).
// Weights live in VGPRs as B-frags (24 frags x 4 VGPR) -- no per-step fetch.
// ---------------------------------------------------------------------------

__global__ __launch_bounds__(256, 1) void rnn_prep(
    const float* __restrict__ W1hh, const float* __restrict__ b1hh,
    const float* __restrict__ W2hh, const float* __restrict__ b2hh,
    const float* __restrict__ W1ho, const float* __restrict__ b1ho,
    unsigned short* __restrict__ acat_hi, unsigned short* __restrict__ acat_lo)
{
    const int idx = blockIdx.x * 256 + threadIdx.x;
    if (idx >= 96 * 64) return;
    const int n = idx >> 6, k = idx & 63;
    const bool hh = n < 48;
    const int col = hh ? n : n - 48;
    float val = 0.f;
    if (col < FF) {
        const float* W1 = hh ? W1hh : W1ho;
        const float* b1 = hh ? b1hh : b1ho;
        if (k < FF) {
            for (int i = 0; i < HIDDEN; ++i)
                val = __builtin_fmaf(W2hh[k * HIDDEN + i], W1[i * FF + col], val);
        } else if (k == 40) {
            val = W1[HIDDEN * FF + col];
        } else if (k == 41) {
            val = b1[col];
            for (int i = 0; i < HIDDEN; ++i)
                val = __builtin_fmaf(b2hh[i], W1[i * FF + col], val);
        }
    }
    const unsigned vb = __builtin_bit_cast(unsigned, val);
    const unsigned short hi = (unsigned short)(vb >> 16);
    const float hif = __builtin_bit_cast(float, (unsigned)hi << 16);
    const float lo = val - hif;
    const unsigned lb = __builtin_bit_cast(unsigned, lo);
    const unsigned short los = (unsigned short)((lb + 0x7FFFu + ((lb >> 16) & 1u)) >> 16);
    acat_hi[idx] = hi;
    acat_lo[idx] = los;
}

__device__ __forceinline__ float sigmoid_fast(float x) {
    const float e = __builtin_amdgcn_exp2f(-x * 1.44269504088896341f);
    return __builtin_amdgcn_rcpf(1.0f + e);
}

__device__ __forceinline__ void split_bf16(float v, unsigned short& hi, unsigned short& lo) {
    const unsigned b = __builtin_bit_cast(unsigned, v);
    hi = (unsigned short)(b >> 16);
    const float hif = __builtin_bit_cast(float, (b & 0xFFFF0000u));
    const float r = v - hif;
    const unsigned rb = __builtin_bit_cast(unsigned, r);
    lo = (unsigned short)((rb + 0x7FFFu + ((rb >> 16) & 1u)) >> 16);
}

// Block = 256 = 4 waves; wave w owns rows [block*64 + 16w, +16), fully
// independent: no __syncthreads anywhere. Per step: 4 ds_read_b128 (S frags)
// -> 36 MFMA -> sigmoid in C-layout -> split-bf16 ds_write -> next step.
// LDS S buffer: [wave][dbuf][hi/lo][16 rows][72 k] ushort (144B row stride,
// 16B aligned, balanced banks). k=40: u-channel, k=41: const 1.0, 42..63: 0.
__global__ __launch_bounds__(256, 1) void rnn_main(
    const float* __restrict__ inputs,
    const unsigned short* __restrict__ acat_hi,
    const unsigned short* __restrict__ acat_lo,
    const float* __restrict__ W1hh, const float* __restrict__ b1hh,
    const float* __restrict__ W1ho, const float* __restrict__ b1ho,
    const float* __restrict__ W2ho, const float* __restrict__ b2ho,
    float* __restrict__ ys)
{
    __shared__ unsigned short s_lds[4][2][2][16][72];   // 36864 B

    const int lane = threadIdx.x & 63;
    const int w = __builtin_amdgcn_readfirstlane(threadIdx.x >> 6);
    const int R0 = blockIdx.x * 64 + w * 16;
    const int c16 = lane & 15;      // col within tile / frag row index m
    const int g = lane >> 4;        // quad: frag k-group

    // ---- preload B-frags (weights) into VGPRs: 24 frags x 16B ----
    short8 Bh[6][2], Bl[6][2];
#pragma unroll
    for (int nb = 0; nb < 6; ++nb)
#pragma unroll
        for (int ks = 0; ks < 2; ++ks) {
            const int idx = (nb * 16 + c16) * 64 + ks * 32 + g * 8;
            Bh[nb][ks] = *(const short8*)(acat_hi + idx);
            Bl[nb][ks] = *(const short8*)(acat_lo + idx);
        }
    const float b2o = b2ho[0];
    // per-lane W2ho for ho tiles (cols >= 40 -> 0)
    float w2o_r[3];
#pragma unroll
    for (int i = 0; i < 3; ++i) {
        const int col = i * 16 + c16;
        w2o_r[i] = (col < FF) ? W2ho[col] : 0.f;
    }

    // ---- init: zero LDS region, set const channel, compute s(0), o(0) ----
    {
        unsigned short* wbase = &s_lds[w][0][0][0][0];   // 4608 ushorts
#pragma unroll
        for (int i = 0; i < 9; ++i)
            ((short8*)wbase)[lane + 64 * i] = (short8)0;
        if (lane < 16) {
            s_lds[w][0][0][lane][41] = 0x3F80;   // bf16 1.0
            s_lds[w][1][0][lane][41] = 0x3F80;
        }
        // s(0) = sigma(u0*wu_raw + b1_raw); o(0) likewise on ho path.
        const int r = lane >> 2;
        const int jc = (lane & 3) * 10;
        const float u0 = inputs[(size_t)(R0 + r) * SEQ_T];
        float opr = 0.f;
#pragma unroll
        for (int jj = 0; jj < 10; ++jj) {
            const int j = jc + jj;
            const float s0 = sigmoid_fast(__builtin_fmaf(u0, W1hh[HIDDEN * FF + j], b1hh[j]));
            unsigned short hi, lo;
            split_bf16(s0, hi, lo);
            s_lds[w][0][0][r][j] = hi;
            s_lds[w][0][1][r][j] = lo;
            const float so = sigmoid_fast(__builtin_fmaf(u0, W1ho[HIDDEN * FF + j], b1ho[j]));
            opr = __builtin_fmaf(so, W2ho[j], opr);
        }
        opr += __shfl_xor(opr, 1);
        opr += __shfl_xor(opr, 2);
        if ((lane & 3) == 0)
            ys[(size_t)(R0 + r) * SEQ_T] = opr + b2o;
        // u(1) into buffer 0's u-channel
        if (lane < 16) {
            const float u1 = inputs[(size_t)(R0 + lane) * SEQ_T + 1];
            unsigned short hi, lo;
            split_bf16(u1, hi, lo);
            s_lds[w][0][0][lane][40] = hi;
            s_lds[w][0][1][lane][40] = lo;
        }
    }

    // ---- main loop ----
    for (int t = 1; t < SEQ_T; ++t) {
        const int rb = (t - 1) & 1;
        const int wb = t & 1;

        // prefetch u(t+1) early (consumed at write phase)
        float u_nx = 0.f;
        if (lane < 16) {
            const int tn = t < SEQ_T - 1 ? t + 1 : SEQ_T - 1;
            u_nx = inputs[(size_t)(R0 + lane) * SEQ_T + tn];
        }

        // S-frags from buffer rb (A-operand: m=lane&15 row, k=g*8+j)
        const unsigned short* bhi = &s_lds[w][rb][0][0][0];
        const unsigned short* blo = &s_lds[w][rb][1][0][0];
        const int off0 = c16 * 72 + g * 8;
        const int off1 = c16 * 72 + 32 + g * 8;
        const short8 sh0 = *(const short8*)(bhi + off0);
        const short8 sh1 = *(const short8*)(bhi + off1);
        const short8 sl0 = *(const short8*)(blo + off0);
        const short8 sl1 = *(const short8*)(blo + off1);

        float4v acc[6];
#pragma unroll
        for (int nb = 0; nb < 6; ++nb) acc[nb] = (float4v)0.f;
#pragma unroll
        for (int nb = 0; nb < 6; ++nb) {
            acc[nb] = __builtin_amdgcn_mfma_f32_16x16x32_bf16(sh0, Bh[nb][0], acc[nb], 0, 0, 0);
            acc[nb] = __builtin_amdgcn_mfma_f32_16x16x32_bf16(sl0, Bh[nb][0], acc[nb], 0, 0, 0);
            acc[nb] = __builtin_amdgcn_mfma_f32_16x16x32_bf16(sh0, Bl[nb][0], acc[nb], 0, 0, 0);
            acc[nb] = __builtin_amdgcn_mfma_f32_16x16x32_bf16(sh1, Bh[nb][1], acc[nb], 0, 0, 0);
            acc[nb] = __builtin_amdgcn_mfma_f32_16x16x32_bf16(sl1, Bh[nb][1], acc[nb], 0, 0, 0);
            acc[nb] = __builtin_amdgcn_mfma_f32_16x16x32_bf16(sh1, Bl[nb][1], acc[nb], 0, 0, 0);
        }

        // ---- hh epilogue: sigma, split, write s(t) to buffer wb ----
        unsigned short* whi = &s_lds[w][wb][0][0][0];
        unsigned short* wlo = &s_lds[w][wb][1][0][0];
#pragma unroll
        for (int tile = 0; tile < 3; ++tile)
#pragma unroll
            for (int reg = 0; reg < 4; ++reg) {
                const float s = sigmoid_fast(acc[tile][reg]);
                unsigned short hi, lo;
                split_bf16(s, hi, lo);
                const int rowl = g * 4 + reg;         // C-layout row
                const int kcol = tile * 16 + c16;     // C-layout col
                if (tile < 2 || c16 < 8) {            // mask pad cols 40..47
                    whi[rowl * 72 + kcol] = hi;
                    wlo[rowl * 72 + kcol] = lo;
                }
            }
        // u(t+1) channel
        if (lane < 16) {
            unsigned short hi, lo;
            split_bf16(u_nx, hi, lo);
            whi[lane * 72 + 40] = hi;
            wlo[lane * 72 + 40] = lo;
        }

        // ---- ho epilogue: o(t) = sigma(zo) @ W2ho + b2o ----
        float op0 = 0.f, op1 = 0.f, op2 = 0.f, op3 = 0.f;
#pragma unroll
        for (int tile = 0; tile < 3; ++tile) {
            op0 = __builtin_fmaf(sigmoid_fast(acc[3 + tile][0]), w2o_r[tile], op0);
            op1 = __builtin_fmaf(sigmoid_fast(acc[3 + tile][1]), w2o_r[tile], op1);
            op2 = __builtin_fmaf(sigmoid_fast(acc[3 + tile][2]), w2o_r[tile], op2);
            op3 = __builtin_fmaf(sigmoid_fast(acc[3 + tile][3]), w2o_r[tile], op3);
        }
#pragma unroll
        for (int m = 1; m < 16; m <<= 1) {
            op0 += __shfl_xor(op0, m);
            op1 += __shfl_xor(op1, m);
            op2 += __shfl_xor(op2, m);
            op3 += __shfl_xor(op3, m);
        }
        if (c16 < 4) {
            const int c4 = lane & 3;
            float ov = c4 == 0 ? op0 : (c4 == 1 ? op1 : (c4 == 2 ? op2 : op3));
            const int row = R0 + g * 4 + c4;
            ys[(size_t)row * SEQ_T + t] = ov + b2o;
        }
    }
}

extern "C" void kernel_launch(void* const* d_in, const int* in_sizes, int n_in,
                              void* d_out, int out_size, void* d_ws, size_t ws_size,
                              hipStream_t stream) {
    const float* inputs = (const float*)d_in[0];
    const float* W1hh   = (const float*)d_in[1];
    const float* b1hh   = (const float*)d_in[2];
    const float* W2hh   = (const float*)d_in[3];
    const float* b2hh   = (const float*)d_in[4];
    const float* W1ho   = (const float*)d_in[5];
    const float* b1ho   = (const float*)d_in[6];
    const float* W2ho   = (const float*)d_in[7];
    const float* b2ho   = (const float*)d_in[8];
    float* ys = (float*)d_out;

    unsigned short* acat_hi = (unsigned short*)d_ws;        // 96*64 ushorts
    unsigned short* acat_lo = acat_hi + 96 * 64;

    const int B = in_sizes[0] / SEQ_T;   // 16384

    rnn_prep<<<(96 * 64 + 255) / 256, 256, 0, stream>>>(
        W1hh, b1hh, W2hh, b2hh, W1ho, b1ho, acat_hi, acat_lo);

    const int blocks = B / 64;           // 256 blocks x 4 waves x 16 rows
    rnn_main<<<blocks, 256, 0, stream>>>(
        inputs, acat_hi, acat_lo, W1hh, b1hh, W1ho, b1ho, W2ho, b2ho, ys);
}